// Round 14
// baseline (221.105 us; speedup 1.0000x reference)
//
#include <hip/hip_runtime.h>
#include <hip/hip_bf16.h>
#include <stdint.h>

// BlockedMLP: out = relu(bsr(relu(x@w1.T+b1))) @ w3.T + b3
// B=4096, D_IN=1024, H=4096, D_OUT=1024, BS=64

typedef __attribute__((ext_vector_type(4))) float f32x4;
typedef __attribute__((ext_vector_type(8))) __bf16 bf16x8;

#define DEV static __device__ __forceinline__

DEV ushort f2bf(float f) {
  union { float f; uint32_t u; } v; v.f = f;
  uint32_t r = v.u + 0x7fffu + ((v.u >> 16) & 1u);  // RNE
  return (ushort)(r >> 16);
}

DEV void gld_lds16(const void* g, void* l) {
  // async global->LDS, 16B/lane; LDS dest = wave-uniform base + lane*16
  __builtin_amdgcn_global_load_lds(
      (const __attribute__((address_space(1))) void*)g,
      (__attribute__((address_space(3))) void*)l, 16, 0, 0);
}

// fused f32->bf16 conversion, block-range partitioned (one branch per kernel,
// no per-iteration array-selection logic). blocks: [0,512) x, [512,1024) w1,
// [1024,1536) w3, [1536,2560) vals.
__global__ void cvt4_kernel(const float* __restrict__ s0, ushort* __restrict__ d0, int n0,
                            const float* __restrict__ s1, ushort* __restrict__ d1, int n1,
                            const float* __restrict__ s2, ushort* __restrict__ d2, int n2,
                            const float* __restrict__ s3, ushort* __restrict__ d3, int n3) {
  const float* s; ushort* d; int n, b0, nb;
  const int b = blockIdx.x;
  if (b < 512)       { s = s0; d = d0; n = n0; b0 = 0;    nb = 512; }
  else if (b < 1024) { s = s1; d = d1; n = n1; b0 = 512;  nb = 512; }
  else if (b < 1536) { s = s2; d = d2; n = n2; b0 = 1024; nb = 512; }
  else               { s = s3; d = d3; n = n3; b0 = 1536; nb = 1024; }
  const int quads = n >> 2;
  for (int idx = (b - b0) * 256 + threadIdx.x; idx < quads; idx += nb * 256) {
    const int i = idx * 4;
    float4 v = *(const float4*)(s + i);
    ushort4 o;
    o.x = f2bf(v.x); o.y = f2bf(v.y); o.z = f2bf(v.z); o.w = f2bf(v.w);
    *(ushort4*)(d + i) = o;
  }
}

// ---------------- dense GEMM stage1 (m97-structure, XCD-pinned 1D grid) ----------------
template <bool RELU, bool OUT_BF16>
__global__ __launch_bounds__(256)
void gemm_nt(const ushort* __restrict__ A, const ushort* __restrict__ W,
             const float* __restrict__ bias, void* __restrict__ Cv,
             int K, int lda, int ldw, int ldc, int ntx, int nty) {
  const int bid = blockIdx.x;
  const int xcd = bid & 7;
  const int j = bid >> 3;
  const int xgrp = ntx >> 3;
  const int bx = xcd + 8 * (j % xgrp);
  const int by = j / xgrp;
  const int i0 = by * 128, j0 = bx * 128;

  __shared__ ushort As[128 * 64];
  __shared__ ushort Ws[128 * 64];
  const int tid = threadIdx.x;
  const int wid = tid >> 6, lane = tid & 63;
  const int wm = wid >> 1, wn = wid & 1;
  f32x4 acc[4][4] = {};

  const int lrow = lane >> 3;
  const int lcol = (lane & 7) * 16;

  for (int k0 = 0; k0 < K; k0 += 64) {
#pragma unroll
    for (int i = 0; i < 4; ++i) {
      int ch = wid * 4 + i;
      int row = ch * 8 + lrow;
      const char* ga = (const char*)A + ((size_t)(i0 + row) * lda + k0) * 2 + lcol;
      gld_lds16(ga, (char*)As + ch * 1024);
      const char* gw = (const char*)W + ((size_t)(j0 + row) * ldw + k0) * 2 + lcol;
      gld_lds16(gw, (char*)Ws + ch * 1024);
    }
    __syncthreads();
#pragma unroll
    for (int kk = 0; kk < 64; kk += 32) {
      const int cl = lane & 15;
      const int kg = kk + (lane >> 4) * 8;
      bf16x8 a[4], b[4];
#pragma unroll
      for (int m = 0; m < 4; ++m)
        a[m] = *(const bf16x8*)&As[(wm * 64 + m * 16 + cl) * 64 + kg];
#pragma unroll
      for (int n = 0; n < 4; ++n)
        b[n] = *(const bf16x8*)&Ws[(wn * 64 + n * 16 + cl) * 64 + kg];
#pragma unroll
      for (int m = 0; m < 4; ++m)
#pragma unroll
        for (int n = 0; n < 4; ++n)
          acc[m][n] = __builtin_amdgcn_mfma_f32_16x16x32_bf16(a[m], b[n], acc[m][n], 0, 0, 0);
    }
    __syncthreads();
  }

  const int cl = lane & 15, r4 = (lane >> 4) * 4;
#pragma unroll
  for (int n = 0; n < 4; ++n) {
    int col = j0 + wn * 64 + n * 16 + cl;
    float bv = bias ? bias[col] : 0.0f;
#pragma unroll
    for (int m = 0; m < 4; ++m) {
      int rowb = i0 + wm * 64 + m * 16 + r4;
#pragma unroll
      for (int r = 0; r < 4; ++r) {
        float v = acc[m][n][r] + bv;
        if (RELU) v = fmaxf(v, 0.0f);
        if (OUT_BF16)
          ((ushort*)Cv)[(size_t)(rowb + r) * ldc + col] = f2bf(v);
        else
          ((float*)Cv)[(size_t)(rowb + r) * ldc + col] = v;
      }
    }
  }
}

// ---- stage3 GEMM: full-K 128x64 tile (bsr skeleton, sequential K; no setprio) ----
__global__ __launch_bounds__(256)
void gemm_n64(const ushort* __restrict__ A, const ushort* __restrict__ W,
              const float* __restrict__ bias, float* __restrict__ Cout,
              int K, int lda, int ldw, int ldc) {
  __shared__ ushort As[2][128 * 64];  // 2 x 16KB
  __shared__ ushort Ws[2][64 * 64];   // 2 x 8KB
  const int tid = threadIdx.x;
  const int wid = tid >> 6, lane = tid & 63;

  const int bid = blockIdx.x;               // 0..511
  const int bx = (bid & 7) + 8 * ((bid >> 3) & 1);  // 0..15 col-tile (XCD-pinned)
  const int by = bid >> 4;                  // 0..31 row-tile
  const int i0 = by * 128, j0 = bx * 64;

  f32x4 acc[2][4] = {};
  const int nt = K >> 6;

  const int lr = lane >> 3;
  const int gsw = ((lane & 7) ^ lr) * 16;

  const char* gb[6];
#pragma unroll
  for (int i = 0; i < 6; ++i) {
    int ch = wid * 6 + i;
    if (ch < 16) gb[i] = (const char*)A + (size_t)(i0 + ch * 8 + lr) * lda * 2 + gsw;
    else         gb[i] = (const char*)W + (size_t)(j0 + (ch - 16) * 8 + lr) * ldw * 2 + gsw;
  }

  auto stage = [&](int buf, int s) {
    const size_t koff = (size_t)s << 7;
#pragma unroll
    for (int i = 0; i < 6; ++i) {
      int ch = wid * 6 + i;
      if (ch < 16) gld_lds16(gb[i] + koff, (char*)As[buf] + ch * 1024);
      else         gld_lds16(gb[i] + koff, (char*)Ws[buf] + (ch - 16) * 1024);
    }
  };

  auto compute = [&](int buf) {
#pragma unroll
    for (int kk = 0; kk < 64; kk += 32) {
      const int cl = lane & 15;
      const int kg = kk + (lane >> 4) * 8;
      const int kx = kg ^ ((cl & 7) << 3);
      bf16x8 a[2], b[4];
#pragma unroll
      for (int m = 0; m < 2; ++m)
        a[m] = *(const bf16x8*)&As[buf][(wid * 32 + m * 16 + cl) * 64 + kx];
#pragma unroll
      for (int nn = 0; nn < 4; ++nn)
        b[nn] = *(const bf16x8*)&Ws[buf][(nn * 16 + cl) * 64 + kx];
#pragma unroll
      for (int m = 0; m < 2; ++m)
#pragma unroll
        for (int nn = 0; nn < 4; ++nn)
          acc[m][nn] = __builtin_amdgcn_mfma_f32_16x16x32_bf16(a[m], b[nn], acc[m][nn], 0, 0, 0);
    }
  };

  int cur = 0;
  stage(0, 0);
  __syncthreads();
  for (int s = 0; s < nt; ++s) {
    if (s + 1 < nt) stage(cur ^ 1, s + 1);
    compute(cur);
    __syncthreads();
    cur ^= 1;
  }

  const int cl = lane & 15, r4 = (lane >> 4) * 4;
#pragma unroll
  for (int nn = 0; nn < 4; ++nn) {
    int col = j0 + nn * 16 + cl;
    const float bv = bias[col];
#pragma unroll
    for (int m = 0; m < 2; ++m) {
      int rowb = i0 + wid * 32 + m * 16 + r4;
#pragma unroll
      for (int r = 0; r < 4; ++r)
        Cout[(size_t)(rowb + r) * ldc + col] = acc[m][nn][r] + bv;
    }
  }
}

// ---- BSR GEMM (R10/R13 structure; setprio removed — T5 null-to-negative on 2-phase) ----
__global__ __launch_bounds__(256)
void bsr_gemm(const ushort* __restrict__ A, const ushort* __restrict__ V,
              const int* __restrict__ crow, const int* __restrict__ colind,
              ushort* __restrict__ C, int Hdim) {
  __shared__ ushort As[2][128 * 64];  // 2 x 16KB
  __shared__ ushort Vs[2][64 * 64];   // 2 x 8KB
  const int tid = threadIdx.x;
  const int wid = tid >> 6, lane = tid & 63;

  const int bid = blockIdx.x;          // 0..2047
  const int xcd = bid & 7;
  const int j = bid >> 3;              // 0..255
  const int tile = xcd + 8 * (j & 3);  // 0..31
  const int br = j >> 2;               // 0..63, br-major
  const int i0 = tile * 128;

  f32x4 acc[2][4] = {};
  const int n0 = crow[br], n1 = crow[br + 1];

  const int lr = lane >> 3;
  const int gsw = ((lane & 7) ^ lr) * 16;

  const char* gb[6];
#pragma unroll
  for (int i = 0; i < 6; ++i) {
    int ch = wid * 6 + i;
    if (ch < 16) gb[i] = (const char*)A + (size_t)(i0 + ch * 8 + lr) * Hdim * 2 + gsw;
    else         gb[i] = (const char*)V + (size_t)((ch - 16) * 8 + lr) * 128 + gsw;
  }

  auto stage = [&](int buf, int n) {
    const int c = colind[n];
    const size_t aoff = (size_t)c << 7;
    const size_t voff = (size_t)n << 13;
#pragma unroll
    for (int i = 0; i < 6; ++i) {
      int ch = wid * 6 + i;
      if (ch < 16) gld_lds16(gb[i] + aoff, (char*)As[buf] + ch * 1024);
      else         gld_lds16(gb[i] + voff, (char*)Vs[buf] + (ch - 16) * 1024);
    }
  };

  auto compute = [&](int buf) {
#pragma unroll
    for (int kk = 0; kk < 64; kk += 32) {
      const int cl = lane & 15;
      const int kg = kk + (lane >> 4) * 8;
      const int kx = kg ^ ((cl & 7) << 3);
      bf16x8 a[2], b[4];
#pragma unroll
      for (int m = 0; m < 2; ++m)
        a[m] = *(const bf16x8*)&As[buf][(wid * 32 + m * 16 + cl) * 64 + kx];
#pragma unroll
      for (int nn = 0; nn < 4; ++nn)
        b[nn] = *(const bf16x8*)&Vs[buf][(nn * 16 + cl) * 64 + kx];
#pragma unroll
      for (int m = 0; m < 2; ++m)
#pragma unroll
        for (int nn = 0; nn < 4; ++nn)
          acc[m][nn] = __builtin_amdgcn_mfma_f32_16x16x32_bf16(a[m], b[nn], acc[m][nn], 0, 0, 0);
    }
  };

  int cur = 0;
  stage(0, n0);
  __syncthreads();
  for (int n = n0; n < n1; ++n) {
    if (n + 1 < n1) stage(cur ^ 1, n + 1);
    compute(cur);
    __syncthreads();
    cur ^= 1;
  }

  const int cl = lane & 15, r4 = (lane >> 4) * 4;
#pragma unroll
  for (int nn = 0; nn < 4; ++nn) {
    int col = br * 64 + nn * 16 + cl;
#pragma unroll
    for (int m = 0; m < 2; ++m) {
      int rowb = i0 + wid * 32 + m * 16 + r4;
#pragma unroll
      for (int r = 0; r < 4; ++r) {
        float v = fmaxf(acc[m][nn][r], 0.0f);
        C[(size_t)(rowb + r) * Hdim + col] = f2bf(v);
      }
    }
  }
}

extern "C" void kernel_launch(void* const* d_in, const int* in_sizes, int n_in,
                              void* d_out, int out_size, void* d_ws, size_t ws_size,
                              hipStream_t stream) {
  const float* x    = (const float*)d_in[0];
  const float* w1   = (const float*)d_in[1];
  const float* b1   = (const float*)d_in[2];
  const float* vals = (const float*)d_in[3];
  const float* w3   = (const float*)d_in[4];
  const float* b3   = (const float*)d_in[5];
  const int* crow   = (const int*)d_in[6];
  const int* colind = (const int*)d_in[7];

  const int Bb = 4096, Din = 1024, H = 4096, Dout = 1024;
  const int nnzb = in_sizes[7];

  char* ws = (char*)d_ws;
  size_t off = 0;
  ushort* xb  = (ushort*)(ws + off); off += (size_t)Bb * Din * 2;
  ushort* w1b = (ushort*)(ws + off); off += (size_t)H * Din * 2;
  ushort* w3b = (ushort*)(ws + off); off += (size_t)Dout * H * 2;
  ushort* vb  = (ushort*)(ws + off); off += (size_t)nnzb * 64 * 64 * 2;
  ushort* h1b = (ushort*)(ws + off); off += (size_t)Bb * H * 2;
  ushort* h2b = (ushort*)(ws + off); off += (size_t)Bb * H * 2;

  // fused conversion, block-range partitioned (grid 2560)
  hipLaunchKernelGGL(cvt4_kernel, dim3(2560), dim3(256), 0, stream,
                     x,    xb,  Bb * Din,
                     w1,   w1b, H * Din,
                     w3,   w3b, Dout * H,
                     vals, vb,  nnzb * 4096);

  // stage 1: h1 = relu(x @ w1^T + b1)   [4096 x 4096] bf16, XCD-pinned grid
  hipLaunchKernelGGL((gemm_nt<true, true>), dim3((H / 128) * (Bb / 128)), dim3(256), 0, stream,
                     xb, w1b, b1, (void*)h1b, Din, Din, Din, H, H / 128, Bb / 128);
  // stage 2: h2 = relu(bsr(h1))         [4096 x 4096] bf16
  hipLaunchKernelGGL(bsr_gemm, dim3((Bb / 128) * (H / 64)), dim3(256), 0, stream,
                     h1b, vb, crow, colind, h2b, H);
  // stage 3: out = h2 @ w3^T + b3       [4096 x 1024] f32, full-K 128x64 tiles
  hipLaunchKernelGGL(gemm_n64, dim3((Dout / 64) * (Bb / 128)), dim3(256), 0, stream,
                     h2b, w3b, b3, (float*)d_out, H, H, H, Dout);
}

// Round 15
// 216.829 us; speedup vs baseline: 1.0197x; 1.0197x over previous
//
#include <hip/hip_runtime.h>
#include <hip/hip_bf16.h>
#include <stdint.h>

// BlockedMLP: out = relu(bsr(relu(x@w1.T+b1))) @ w3.T + b3
// B=4096, D_IN=1024, H=4096, D_OUT=1024, BS=64
// R15 = exact revert to R13 (best measured: 217.6us). R14's micros regressed.

typedef __attribute__((ext_vector_type(4))) float f32x4;
typedef __attribute__((ext_vector_type(8))) __bf16 bf16x8;

#define DEV static __device__ __forceinline__

DEV ushort f2bf(float f) {
  union { float f; uint32_t u; } v; v.f = f;
  uint32_t r = v.u + 0x7fffu + ((v.u >> 16) & 1u);  // RNE
  return (ushort)(r >> 16);
}

DEV void gld_lds16(const void* g, void* l) {
  // async global->LDS, 16B/lane; LDS dest = wave-uniform base + lane*16
  __builtin_amdgcn_global_load_lds(
      (const __attribute__((address_space(1))) void*)g,
      (__attribute__((address_space(3))) void*)l, 16, 0, 0);
}

// fused f32->bf16 conversion of 4 arrays in one launch (grid-stride, R7 form)
__global__ void cvt4_kernel(const float* __restrict__ s0, ushort* __restrict__ d0, int n0,
                            const float* __restrict__ s1, ushort* __restrict__ d1, int n1,
                            const float* __restrict__ s2, ushort* __restrict__ d2, int n2,
                            const float* __restrict__ s3, ushort* __restrict__ d3, int n3) {
  const int total = (n0 + n1 + n2 + n3) >> 2;
  for (int idx = blockIdx.x * blockDim.x + threadIdx.x; idx < total;
       idx += gridDim.x * blockDim.x) {
    int i = idx * 4;
    const float* s; ushort* d;
    if (i < n0)               { s = s0; d = d0; }
    else if ((i -= n0) < n1)  { s = s1; d = d1; }
    else if ((i -= n1) < n2)  { s = s2; d = d2; }
    else                      { i -= n2; s = s3; d = d3; }
    float4 v = *(const float4*)(s + i);
    ushort4 o;
    o.x = f2bf(v.x); o.y = f2bf(v.y); o.z = f2bf(v.z); o.w = f2bf(v.w);
    *(ushort4*)(d + i) = o;
  }
}

// ---------------- dense GEMM stage1 (m97-structure, XCD-pinned 1D grid) ----------------
template <bool RELU, bool OUT_BF16>
__global__ __launch_bounds__(256)
void gemm_nt(const ushort* __restrict__ A, const ushort* __restrict__ W,
             const float* __restrict__ bias, void* __restrict__ Cv,
             int K, int lda, int ldw, int ldc, int ntx, int nty) {
  const int bid = blockIdx.x;
  const int xcd = bid & 7;
  const int j = bid >> 3;
  const int xgrp = ntx >> 3;
  const int bx = xcd + 8 * (j % xgrp);
  const int by = j / xgrp;
  const int i0 = by * 128, j0 = bx * 128;

  __shared__ ushort As[128 * 64];
  __shared__ ushort Ws[128 * 64];
  const int tid = threadIdx.x;
  const int wid = tid >> 6, lane = tid & 63;
  const int wm = wid >> 1, wn = wid & 1;
  f32x4 acc[4][4] = {};

  const int lrow = lane >> 3;
  const int lcol = (lane & 7) * 16;

  for (int k0 = 0; k0 < K; k0 += 64) {
#pragma unroll
    for (int i = 0; i < 4; ++i) {
      int ch = wid * 4 + i;
      int row = ch * 8 + lrow;
      const char* ga = (const char*)A + ((size_t)(i0 + row) * lda + k0) * 2 + lcol;
      gld_lds16(ga, (char*)As + ch * 1024);
      const char* gw = (const char*)W + ((size_t)(j0 + row) * ldw + k0) * 2 + lcol;
      gld_lds16(gw, (char*)Ws + ch * 1024);
    }
    __syncthreads();
#pragma unroll
    for (int kk = 0; kk < 64; kk += 32) {
      const int cl = lane & 15;
      const int kg = kk + (lane >> 4) * 8;
      bf16x8 a[4], b[4];
#pragma unroll
      for (int m = 0; m < 4; ++m)
        a[m] = *(const bf16x8*)&As[(wm * 64 + m * 16 + cl) * 64 + kg];
#pragma unroll
      for (int n = 0; n < 4; ++n)
        b[n] = *(const bf16x8*)&Ws[(wn * 64 + n * 16 + cl) * 64 + kg];
#pragma unroll
      for (int m = 0; m < 4; ++m)
#pragma unroll
        for (int n = 0; n < 4; ++n)
          acc[m][n] = __builtin_amdgcn_mfma_f32_16x16x32_bf16(a[m], b[n], acc[m][n], 0, 0, 0);
    }
    __syncthreads();
  }

  const int cl = lane & 15, r4 = (lane >> 4) * 4;
#pragma unroll
  for (int n = 0; n < 4; ++n) {
    int col = j0 + wn * 64 + n * 16 + cl;
    float bv = bias ? bias[col] : 0.0f;
#pragma unroll
    for (int m = 0; m < 4; ++m) {
      int rowb = i0 + wm * 64 + m * 16 + r4;
#pragma unroll
      for (int r = 0; r < 4; ++r) {
        float v = acc[m][n][r] + bv;
        if (RELU) v = fmaxf(v, 0.0f);
        if (OUT_BF16)
          ((ushort*)Cv)[(size_t)(rowb + r) * ldc + col] = f2bf(v);
        else
          ((float*)Cv)[(size_t)(rowb + r) * ldc + col] = v;
      }
    }
  }
}

// ---- stage3 GEMM: full-K 128x64 tile (bsr_gemm skeleton, sequential K) ----
__global__ __launch_bounds__(256)
void gemm_n64(const ushort* __restrict__ A, const ushort* __restrict__ W,
              const float* __restrict__ bias, float* __restrict__ Cout,
              int K, int lda, int ldw, int ldc) {
  __shared__ ushort As[2][128 * 64];  // 2 x 16KB
  __shared__ ushort Ws[2][64 * 64];   // 2 x 8KB
  const int tid = threadIdx.x;
  const int wid = tid >> 6, lane = tid & 63;

  const int bid = blockIdx.x;               // 0..511
  const int bx = (bid & 7) + 8 * ((bid >> 3) & 1);  // 0..15 col-tile (XCD-pinned)
  const int by = bid >> 4;                  // 0..31 row-tile
  const int i0 = by * 128, j0 = bx * 64;

  f32x4 acc[2][4] = {};
  const int nt = K >> 6;

  const int lr = lane >> 3;
  const int gsw = ((lane & 7) ^ lr) * 16;

  const char* gb[6];
#pragma unroll
  for (int i = 0; i < 6; ++i) {
    int ch = wid * 6 + i;
    if (ch < 16) gb[i] = (const char*)A + (size_t)(i0 + ch * 8 + lr) * lda * 2 + gsw;
    else         gb[i] = (const char*)W + (size_t)(j0 + (ch - 16) * 8 + lr) * ldw * 2 + gsw;
  }

  auto stage = [&](int buf, int s) {
    const size_t koff = (size_t)s << 7;
#pragma unroll
    for (int i = 0; i < 6; ++i) {
      int ch = wid * 6 + i;
      if (ch < 16) gld_lds16(gb[i] + koff, (char*)As[buf] + ch * 1024);
      else         gld_lds16(gb[i] + koff, (char*)Ws[buf] + (ch - 16) * 1024);
    }
  };

  auto compute = [&](int buf) {
#pragma unroll
    for (int kk = 0; kk < 64; kk += 32) {
      const int cl = lane & 15;
      const int kg = kk + (lane >> 4) * 8;
      const int kx = kg ^ ((cl & 7) << 3);
      bf16x8 a[2], b[4];
#pragma unroll
      for (int m = 0; m < 2; ++m)
        a[m] = *(const bf16x8*)&As[buf][(wid * 32 + m * 16 + cl) * 64 + kx];
#pragma unroll
      for (int nn = 0; nn < 4; ++nn)
        b[nn] = *(const bf16x8*)&Ws[buf][(nn * 16 + cl) * 64 + kx];
      __builtin_amdgcn_s_setprio(1);
#pragma unroll
      for (int m = 0; m < 2; ++m)
#pragma unroll
        for (int nn = 0; nn < 4; ++nn)
          acc[m][nn] = __builtin_amdgcn_mfma_f32_16x16x32_bf16(a[m], b[nn], acc[m][nn], 0, 0, 0);
      __builtin_amdgcn_s_setprio(0);
    }
  };

  int cur = 0;
  stage(0, 0);
  __syncthreads();
  for (int s = 0; s < nt; ++s) {
    if (s + 1 < nt) stage(cur ^ 1, s + 1);
    compute(cur);
    __syncthreads();
    cur ^= 1;
  }

  const int cl = lane & 15, r4 = (lane >> 4) * 4;
#pragma unroll
  for (int nn = 0; nn < 4; ++nn) {
    int col = j0 + nn * 16 + cl;
    const float bv = bias[col];
#pragma unroll
    for (int m = 0; m < 2; ++m) {
      int rowb = i0 + wid * 32 + m * 16 + r4;
#pragma unroll
      for (int r = 0; r < 4; ++r)
        Cout[(size_t)(rowb + r) * ldc + col] = acc[m][nn][r] + bv;
    }
  }
}

// ---- BSR GEMM (R10 structure, with setprio: best measured ~93.5us) ----
__global__ __launch_bounds__(256)
void bsr_gemm(const ushort* __restrict__ A, const ushort* __restrict__ V,
              const int* __restrict__ crow, const int* __restrict__ colind,
              ushort* __restrict__ C, int Hdim) {
  __shared__ ushort As[2][128 * 64];  // 2 x 16KB
  __shared__ ushort Vs[2][64 * 64];   // 2 x 8KB
  const int tid = threadIdx.x;
  const int wid = tid >> 6, lane = tid & 63;

  const int bid = blockIdx.x;          // 0..2047
  const int xcd = bid & 7;
  const int j = bid >> 3;              // 0..255
  const int tile = xcd + 8 * (j & 3);  // 0..31
  const int br = j >> 2;               // 0..63, br-major
  const int i0 = tile * 128;

  f32x4 acc[2][4] = {};
  const int n0 = crow[br], n1 = crow[br + 1];

  const int lr = lane >> 3;
  const int gsw = ((lane & 7) ^ lr) * 16;

  const char* gb[6];
#pragma unroll
  for (int i = 0; i < 6; ++i) {
    int ch = wid * 6 + i;
    if (ch < 16) gb[i] = (const char*)A + (size_t)(i0 + ch * 8 + lr) * Hdim * 2 + gsw;
    else         gb[i] = (const char*)V + (size_t)((ch - 16) * 8 + lr) * 128 + gsw;
  }

  auto stage = [&](int buf, int n) {
    const int c = colind[n];
    const size_t aoff = (size_t)c << 7;
    const size_t voff = (size_t)n << 13;
#pragma unroll
    for (int i = 0; i < 6; ++i) {
      int ch = wid * 6 + i;
      if (ch < 16) gld_lds16(gb[i] + aoff, (char*)As[buf] + ch * 1024);
      else         gld_lds16(gb[i] + voff, (char*)Vs[buf] + (ch - 16) * 1024);
    }
  };

  auto compute = [&](int buf) {
#pragma unroll
    for (int kk = 0; kk < 64; kk += 32) {
      const int cl = lane & 15;
      const int kg = kk + (lane >> 4) * 8;
      const int kx = kg ^ ((cl & 7) << 3);
      bf16x8 a[2], b[4];
#pragma unroll
      for (int m = 0; m < 2; ++m)
        a[m] = *(const bf16x8*)&As[buf][(wid * 32 + m * 16 + cl) * 64 + kx];
#pragma unroll
      for (int nn = 0; nn < 4; ++nn)
        b[nn] = *(const bf16x8*)&Vs[buf][(nn * 16 + cl) * 64 + kx];
      __builtin_amdgcn_s_setprio(1);
#pragma unroll
      for (int m = 0; m < 2; ++m)
#pragma unroll
        for (int nn = 0; nn < 4; ++nn)
          acc[m][nn] = __builtin_amdgcn_mfma_f32_16x16x32_bf16(a[m], b[nn], acc[m][nn], 0, 0, 0);
      __builtin_amdgcn_s_setprio(0);
    }
  };

  int cur = 0;
  stage(0, n0);
  __syncthreads();
  for (int n = n0; n < n1; ++n) {
    if (n + 1 < n1) stage(cur ^ 1, n + 1);
    compute(cur);
    __syncthreads();
    cur ^= 1;
  }

  const int cl = lane & 15, r4 = (lane >> 4) * 4;
#pragma unroll
  for (int nn = 0; nn < 4; ++nn) {
    int col = br * 64 + nn * 16 + cl;
#pragma unroll
    for (int m = 0; m < 2; ++m) {
      int rowb = i0 + wid * 32 + m * 16 + r4;
#pragma unroll
      for (int r = 0; r < 4; ++r) {
        float v = fmaxf(acc[m][nn][r], 0.0f);
        C[(size_t)(rowb + r) * Hdim + col] = f2bf(v);
      }
    }
  }
}

extern "C" void kernel_launch(void* const* d_in, const int* in_sizes, int n_in,
                              void* d_out, int out_size, void* d_ws, size_t ws_size,
                              hipStream_t stream) {
  const float* x    = (const float*)d_in[0];
  const float* w1   = (const float*)d_in[1];
  const float* b1   = (const float*)d_in[2];
  const float* vals = (const float*)d_in[3];
  const float* w3   = (const float*)d_in[4];
  const float* b3   = (const float*)d_in[5];
  const int* crow   = (const int*)d_in[6];
  const int* colind = (const int*)d_in[7];

  const int Bb = 4096, Din = 1024, H = 4096, Dout = 1024;
  const int nnzb = in_sizes[7];

  char* ws = (char*)d_ws;
  size_t off = 0;
  ushort* xb  = (ushort*)(ws + off); off += (size_t)Bb * Din * 2;
  ushort* w1b = (ushort*)(ws + off); off += (size_t)H * Din * 2;
  ushort* w3b = (ushort*)(ws + off); off += (size_t)Dout * H * 2;
  ushort* vb  = (ushort*)(ws + off); off += (size_t)nnzb * 64 * 64 * 2;
  ushort* h1b = (ushort*)(ws + off); off += (size_t)Bb * H * 2;
  ushort* h2b = (ushort*)(ws + off); off += (size_t)Bb * H * 2;

  // one fused conversion launch for x, w1, w3, vals
  hipLaunchKernelGGL(cvt4_kernel, dim3(2048), dim3(256), 0, stream,
                     x,    xb,  Bb * Din,
                     w1,   w1b, H * Din,
                     w3,   w3b, Dout * H,
                     vals, vb,  nnzb * 4096);

  // stage 1: h1 = relu(x @ w1^T + b1)   [4096 x 4096] bf16, XCD-pinned grid
  hipLaunchKernelGGL((gemm_nt<true, true>), dim3((H / 128) * (Bb / 128)), dim3(256), 0, stream,
                     xb, w1b, b1, (void*)h1b, Din, Din, Din, H, H / 128, Bb / 128);
  // stage 2: h2 = relu(bsr(h1))         [4096 x 4096] bf16
  hipLaunchKernelGGL(bsr_gemm, dim3((Bb / 128) * (H / 64)), dim3(256), 0, stream,
                     h1b, vb, crow, colind, h2b, H);
  // stage 3: out = h2 @ w3^T + b3       [4096 x 1024] f32, full-K 128x64 tiles
  hipLaunchKernelGGL(gemm_n64, dim3((Dout / 64) * (Bb / 128)), dim3(256), 0, stream,
                     h2b, w3b, b3, (float*)d_out, H, H, H, Dout);
}